// Round 5
// baseline (251.926 us; speedup 1.0000x reference)
//
#include <hip/hip_runtime.h>
#include <math.h>

// Problem constants
#define B_    32
#define S_    2048
#define CIN_  256
#define COUT_ 256
#define K_    16
#define TOUT_ 2033   // S - K + 1
#define RTOT_ 4096   // CIN * K reduction length

typedef __bf16 bf16x4 __attribute__((ext_vector_type(4)));
typedef __bf16 bf16x8 __attribute__((ext_vector_type(8)));
typedef float  f32x4  __attribute__((ext_vector_type(4)));

#define GLOBAL_AS __attribute__((address_space(1)))
#define LDS_AS    __attribute__((address_space(3)))

__device__ __forceinline__ void gload_lds16(const void* g, void* l) {
  // async global -> LDS: per-lane global gather, LDS dest = wave-uniform base + lane*16
  __builtin_amdgcn_global_load_lds((const GLOBAL_AS void*)g, (LDS_AS void*)l, 16, 0, 0);
}

// ---------------------------------------------------------------------------
// Build B^T in bf16:  wt[o][kk*256 + i] = cos(ph[kk])*w_real[o][i][kk]
//                                        - sin(ph[kk])*w_imag[o][i][kk]
// Row-major [COUT][RTOT] = 2 MB workspace (keep ws footprint tiny).
// ---------------------------------------------------------------------------
__global__ void __launch_bounds__(256) build_wt_kernel(const float* __restrict__ wr,
                                                       const float* __restrict__ wi,
                                                       const float* __restrict__ ph,
                                                       __bf16* __restrict__ wt) {
  int t = blockIdx.x * 256 + threadIdx.x;   // 65536 threads: one per (o,i)
  int o = t >> 8, i = t & 255;
  const float4* wr4 = (const float4*)(wr + (size_t)(o * CIN_ + i) * K_);
  const float4* wi4 = (const float4*)(wi + (size_t)(o * CIN_ + i) * K_);
  float re[16], im[16];
  #pragma unroll
  for (int v = 0; v < 4; v++) {
    float4 a = wr4[v];
    re[4*v+0]=a.x; re[4*v+1]=a.y; re[4*v+2]=a.z; re[4*v+3]=a.w;
    float4 b = wi4[v];
    im[4*v+0]=b.x; im[4*v+1]=b.y; im[4*v+2]=b.z; im[4*v+3]=b.w;
  }
  #pragma unroll
  for (int kk = 0; kk < K_; kk++) {
    float p = ph[kk];
    wt[(size_t)o * RTOT_ + kk * CIN_ + i] = (__bf16)(cosf(p)*re[kk] - sinf(p)*im[kk]);
  }
}

// ---------------------------------------------------------------------------
// Main: implicit-GEMM conv, software-pipelined with PRE-BARRIER fragment
// reads (m201 phase order) + T2 swizzle + counted vmcnt + setprio.
//
// Round-5 restructure: round-4 showed conflicts=0 yet MfmaUtil stuck ~47%:
// the stall is the post-barrier ds_read burst (all waves dump 32 b128 reads
// into a ~72%-loaded LDS in lockstep, ~150-300 cyc fragment-wait before
// every MFMA cluster). Fix: read iter j+1's fragments BEFORE barrier_j so
// LDS service overlaps barrier convergence; MFMA starts immediately at
// barrier exit (operands loaded last iter).
//   - af pre-barrier: As stable within ic (boundary iters read af after the
//     As-restage barrier instead).
//   - bfrag pre-barrier requires SELF-STAGING: wave w stages its own read
//     region (rows wn*64..+63, 4 gloads; wave pairs (0,2)/(1,3) write
//     duplicate identical bytes - benign). Own vmcnt(4) then retires own
//     B(j+1) -> bfrag read is single-wave-correct pre-barrier.
//   - End of iter: MFMA -> read af(j+1) -> vmcnt(4) -> read bfrag(j+1) ->
//     RAW s_barrier (no drain). WAR on the reused af/bfrag registers orders
//     reads after MFMA; zero extra VGPRs (live ranges rotate on back-edge).
//   - Ring-3 ledger (1 barrier/iter => all waves in same iter j): stage
//     writes (j+2)%3; pre-barrier reads touch (j+1)%3; current MFMA regs
//     came from j%3 (consumed pre-barrier). Overwrite of buf j%3 (stage at
//     iter j+1) is post-barrier_j; its last reads completed at iter j's
//     MFMA operand-wait (pre-barrier_j). All distinct/retired.
//   - vmcnt ledger: at the wait, outstanding = B(j+1) 4 + B(j+2) 4 ->
//     vmcnt(4) retires B(j+1). j==126 staged nothing -> vmcnt(0).
//   - T2 swizzle (round 4, conflicts 1.678e7 -> 0): byte ^= ((row>>1)&3)<<4;
//     As swizzled on ds_write+read; Bs pre-swizzled on the GLOBAL source
//     (slot = (lane&3) ^ ((lane>>3)&3)), linear LDS dest (rule #21).
//   - T14 reg-prefetch of A stays dropped (round-2: spilled past the
//     128-reg cap: 64 AGPR acc + frag + pref > 128 -> scratch, +27MB HBM).
//   - launch_bounds(256,4) + LDS 33792 B -> 4 blocks/CU (grid exactly 4/CU;
//     round-1 showed 3/CU costs a 256-block tail round).
// ---------------------------------------------------------------------------
__global__ void __launch_bounds__(256, 4) conv_mfma_kernel(const float* __restrict__ xg,
                                                           const __bf16* __restrict__ wt,
                                                           float* __restrict__ out) {
  __shared__ __align__(16) __bf16 As[144 * 32];       // [row t-local][32 ch] 9216 B
  __shared__ __align__(16) __bf16 Bs[3][128 * 32];    // ring of [row o-local][32 k] 3x8192 B

  const int bx = blockIdx.x;
  const int nb = bx & 1;          // o-block 0..1
  const int mb = (bx >> 1) & 15;  // t-block 0..15
  const int b  = bx >> 5;         // batch   0..31

  const int tid  = threadIdx.x;
  const int w    = tid >> 6;
  const int lane = tid & 63;
  const int wm   = w >> 1, wn = w & 1;
  const int n16  = lane & 15, q = lane >> 4;

  const int t0 = mb * 128;
  const int o0 = nb * 128;

  const float* xbase = xg + (size_t)b * (S_ * CIN_);

  // A staging geometry (reg round-trip): thread -> (row sr, 4 fp32 at col sc)
  const int sr = tid >> 3;        // 0..31
  const int sc = (tid & 7) * 4;   // fp32/bf16 col offset (8B chunk; slot = sc>>3)
  // B self-staging geometry: wave w covers rows wn*64 + p*16 + (lane>>2),
  // p=0..3 (its own read region). Source slot carries the T2 pre-swizzle.
  const int br2 = wn * 64 + (lane >> 2);
  const int bc  = (((lane & 3) ^ ((lane >> 3) & 3))) * 8;  // T2 pre-swizzled source slot

  // T2 read-side slot swizzle for Bs (row bits [2:1] = n16 bits [2:1])
  const int bswz = (n16 >> 1) & 3;

  f32x4 acc[4][4];
  #pragma unroll
  for (int im_ = 0; im_ < 4; im_++)
    #pragma unroll
    for (int in_ = 0; in_ < 4; in_++)
      acc[im_][in_] = {0.f, 0.f, 0.f, 0.f};

  // ---- Stage A for channel group ic: rows 0..143 (x rows t0.., clamped) ----
  // T2: 8B chunk (orig col sc) lands at col sc ^ (((r>>1)&3)<<3).
  auto stage_a = [&](int ic) {
    const float* xcol = xbase + ic * 32 + sc;
    #pragma unroll
    for (int p = 0; p < 4; p++) {
      int r = p * 32 + sr;
      int rg = t0 + r; rg = (rg < S_) ? rg : (S_ - 1);
      float4 v = *(const float4*)(xcol + (size_t)rg * CIN_);
      bf16x4 o4; o4[0]=(__bf16)v.x; o4[1]=(__bf16)v.y; o4[2]=(__bf16)v.z; o4[3]=(__bf16)v.w;
      *(bf16x4*)(As + r * 32 + (sc ^ (((r >> 1) & 3) << 3))) = o4;
    }
    if (tid < 128) {  // tail rows 128..143
      int r = 128 + sr;
      int rg = t0 + r; rg = (rg < S_) ? rg : (S_ - 1);
      float4 v = *(const float4*)(xcol + (size_t)rg * CIN_);
      bf16x4 o4; o4[0]=(__bf16)v.x; o4[1]=(__bf16)v.y; o4[2]=(__bf16)v.z; o4[3]=(__bf16)v.w;
      *(bf16x4*)(As + r * 32 + (sc ^ (((r >> 1) & 3) << 3))) = o4;
    }
  };

  // ---- Self-stage B chunk for step j into ring buffer buf (4 gloads/wave,
  // wave's own read region rows wn*64..+63) ----
  auto stage_b = [&](int j, int buf) {
    const int kk = j & 15;
    const int i0 = (j >> 4) * 32;
    const __bf16* wcol = wt + (size_t)kk * CIN_ + i0 + bc;
    __bf16* dst = &Bs[0][0] + buf * (128 * 32) + (wn * 64) * 32;
    #pragma unroll
    for (int p = 0; p < 4; p++) {
      int orow = o0 + br2 + p * 16;
      gload_lds16(wcol + (size_t)orow * RTOT_, (void*)(dst + p * 16 * 32));
    }
  };

  // ---- Fragment reads (reused registers; WAR vs MFMA orders them) ----
  bf16x8 af[4], bfrag[4];
  auto read_af = [&](int kp) {      // kp = kk of the target iteration
    const int aswz = ((kp + n16) >> 1) & 3;
    #pragma unroll
    for (int jm = 0; jm < 4; jm++) {
      int row = kp + wm * 64 + jm * 16 + n16;    // A[m=lane&15][k=q*8+j]
      af[jm] = *(const bf16x8*)(As + row * 32 + ((q ^ aswz) * 8));
    }
  };
  auto read_bf = [&](int buf) {
    const __bf16* bsr = &Bs[0][0] + buf * (128 * 32);
    #pragma unroll
    for (int jn = 0; jn < 4; jn++) {
      int row = wn * 64 + jn * 16 + n16;         // B^T[n=lane&15][k=q*8+j]
      bfrag[jn] = *(const bf16x8*)(bsr + row * 32 + ((q ^ bswz) * 8));
    }
  };

  // ---- Prologue: A(ic=0); B(0), B(1) self-staged; own vmcnt(4) retires
  // B(0); barrier makes As + all waves' B(0) visible; read frags(0).
  stage_a(0);
  stage_b(0, 0);
  stage_b(1, 1);
  asm volatile("s_waitcnt vmcnt(4) lgkmcnt(0)\n\ts_barrier" ::: "memory");
  read_af(0);
  read_bf(0);

  int sw = 2;   // stage buffer = (j+2) % 3
  int fr = 1;   // frag-read buffer = (j+1) % 3
  #pragma unroll 1
  for (int j = 0; j < 128; ++j) {
    const int kk = j & 15;

    if (j + 2 < 128) stage_b(j + 2, sw);   // prefetch depth 2 (wave-uniform)

    __builtin_amdgcn_s_setprio(1);
    #pragma unroll
    for (int jm = 0; jm < 4; jm++)
      #pragma unroll
      for (int jn = 0; jn < 4; jn++)
        acc[jm][jn] = __builtin_amdgcn_mfma_f32_16x16x32_bf16(af[jm], bfrag[jn], acc[jm][jn], 0, 0, 0);
    __builtin_amdgcn_s_setprio(0);

    if (j == 127) break;               // last step: no tail work

    const bool bdry = (kk == 15);
    if (!bdry) read_af(kk + 1);        // pre-barrier: As stable within ic

    // Own-wave counted wait: retires own B(j+1) (self-staged region),
    // keeps B(j+2) in flight. j==126 staged nothing -> drain fully.
    if (j <= 125) asm volatile("s_waitcnt vmcnt(4)" ::: "memory");
    else          asm volatile("s_waitcnt vmcnt(0)" ::: "memory");
    read_bf(fr);                       // pre-barrier: self-staged rows only

    asm volatile("s_barrier" ::: "memory");   // raw barrier: no drains

    if (bdry) {
      // ic boundary: all As reads for this ic completed pre-barrier (the
      // MFMA operand-waits). Restage, fence ds_writes, then read new af.
      stage_a((j + 1) >> 4);
      asm volatile("s_waitcnt lgkmcnt(0)\n\ts_barrier" ::: "memory");
      read_af(0);
    }

    sw = (sw == 2) ? 0 : sw + 1;
    fr = (fr == 2) ? 0 : fr + 1;
  }

  // ---- Epilogue: C/D layout col = lane&15, row = (lane>>4)*4 + reg ----
  float* obase = out + (size_t)b * TOUT_ * COUT_;
  #pragma unroll
  for (int jm = 0; jm < 4; jm++) {
    #pragma unroll
    for (int r = 0; r < 4; r++) {
      int t = t0 + wm * 64 + jm * 16 + q * 4 + r;
      if (t < TOUT_) {
        float* orow = obase + (size_t)t * COUT_ + o0 + wn * 64 + n16;
        #pragma unroll
        for (int jn = 0; jn < 4; jn++)
          orow[jn * 16] = acc[jm][jn][r];
      }
    }
  }
}

// ---------------------------------------------------------------------------
extern "C" void kernel_launch(void* const* d_in, const int* in_sizes, int n_in,
                              void* d_out, int out_size, void* d_ws, size_t ws_size,
                              hipStream_t stream) {
  const float* x  = (const float*)d_in[0];
  const float* wr = (const float*)d_in[1];
  const float* wi = (const float*)d_in[2];
  const float* ph = (const float*)d_in[3];
  float* out = (float*)d_out;

  __bf16* wt = (__bf16*)d_ws;  // 2 MB only

  build_wt_kernel<<<dim3((COUT_ * CIN_) / 256), dim3(256), 0, stream>>>(wr, wi, ph, wt);
  conv_mfma_kernel<<<dim3(B_ * 16 * 2), dim3(256), 0, stream>>>(x, wt, out);
}

// Round 6
// 233.501 us; speedup vs baseline: 1.0789x; 1.0789x over previous
//
#include <hip/hip_runtime.h>
#include <math.h>

// Problem constants
#define B_    32
#define S_    2048
#define CIN_  256
#define COUT_ 256
#define K_    16
#define TOUT_ 2033   // S - K + 1
#define RTOT_ 4096   // elements per wt2 output row = 128 steps * 32

typedef __bf16 bf16x4 __attribute__((ext_vector_type(4)));
typedef __bf16 bf16x8 __attribute__((ext_vector_type(8)));
typedef float  f32x4  __attribute__((ext_vector_type(4)));

#define GLOBAL_AS __attribute__((address_space(1)))
#define LDS_AS    __attribute__((address_space(3)))

__device__ __forceinline__ void gload_lds16(const void* g, void* l) {
  // async global -> LDS: per-lane global gather, LDS dest = wave-uniform base + lane*16
  __builtin_amdgcn_global_load_lds((const GLOBAL_AS void*)g, (LDS_AS void*)l, 16, 0, 0);
}

// ---------------------------------------------------------------------------
// Build B^T in bf16, K-order (tap-pair, ch16):
//   step j = (ch_group g = i>>4)*8 + (tap pair tp = k>>1), elem e = ((k&1)<<4)|(i&15)
//   wt2[o][j][e] = cos(ph[k])*w_real[o][i][k] - sin(ph[k])*w_imag[o][i][k]
// Row-major [COUT][128*32] = 2 MB workspace. The (tap,ch) e-map is used
// IDENTICALLY on the A side, so the MFMA contraction is unchanged.
// ---------------------------------------------------------------------------
__global__ void __launch_bounds__(256) build_wt_kernel(const float* __restrict__ wr,
                                                       const float* __restrict__ wi,
                                                       const float* __restrict__ ph,
                                                       __bf16* __restrict__ wt) {
  int t = blockIdx.x * 256 + threadIdx.x;   // 65536 threads: one per (o,i)
  int o = t >> 8, i = t & 255;
  const float4* wr4 = (const float4*)(wr + (size_t)(o * CIN_ + i) * K_);
  const float4* wi4 = (const float4*)(wi + (size_t)(o * CIN_ + i) * K_);
  float re[16], im[16];
  #pragma unroll
  for (int v = 0; v < 4; v++) {
    float4 a = wr4[v];
    re[4*v+0]=a.x; re[4*v+1]=a.y; re[4*v+2]=a.z; re[4*v+3]=a.w;
    float4 b = wi4[v];
    im[4*v+0]=b.x; im[4*v+1]=b.y; im[4*v+2]=b.z; im[4*v+3]=b.w;
  }
  __bf16* wrow = wt + (size_t)o * RTOT_ + (i >> 4) * 256 + (i & 15);
  #pragma unroll
  for (int k = 0; k < K_; k++) {
    float p = ph[k];
    wrow[(k >> 1) * 32 + ((k & 1) << 4)] = (__bf16)(cosf(p)*re[k] - sinf(p)*im[k]);
  }
}

// ---------------------------------------------------------------------------
// Main: implicit-GEMM conv, depth-3 pipelined with PRE-BARRIER fragment reads.
//
// Round-6 design (fixes round-5's failure without its cost):
//  - Round 5's pre-barrier bfrag read needed cross-wave visibility and got it
//    by SELF-STAGING (2x duplicate loads: +13MB FETCH, +VALU, +LDS writes ->
//    regression). Depth-3 gives the guarantee for free: each wave's
//    end-of-iter vmcnt(2) at iter t retires B(t+2), so ALL waves' B(j+1)
//    loads are retired before barrier_{j-1} -> reading bfrag(j+1) anywhere
//    in iter j is safe with the ORIGINAL 2-gload cross-wave staging.
//  - Depth 3 => ring-4 Bs = 32768 B. To stay under the 40960 B / 4-blocks-CU
//    cliff (round 1: 1KB over = tail-round disaster), As shrinks to 16
//    channels: K-step regrouped as (tap-pair x 16ch), e = (tap&1, ch16).
//    Same 128 steps, same 8KB B-chunks, same fragment/MFMA geometry; only
//    the e->(tap,ch) map changes, identically on A and B (build_wt above).
//    As = 143 rows x 16 ch x 2B = 4576 (alloc 4608). Total LDS 37376 -> 4/CU.
//  - As rows are 32 B => unswizzled af reads would 4-way conflict. Involution
//    byte ^= ((byte>>8)&7)<<4  (row>>3 into 16B-slot bits, non-overlapping
//    => true involution), applied on As write AND read: 2-way = free.
//  - Bs T2 swizzle unchanged (measured 0 conflicts): source slot
//    (lane&3)^((lane>>3)&3), read slot q^((n16>>1)&3).
//  - Steady-state iter j: stage_b(j+3) | MFMA(j) | read_af(j+1) | vmcnt(2)
//    [retires B(j+2), keeps B(j+3)] | read_bf(j+1) | raw s_barrier.
//    ds_reads drain during barrier-wait; MFMA(j+1) starts immediately.
//  - Ring-4 ledger (1 barrier/iter => skew <= 1 iter): iter-j writer hits
//    buf (j+3)&3 = (j-1)&3, whose last reads (read_bf(j-1), iter j-2)
//    completed 2 barriers earlier. Pre-barrier read buf (j+1)&3 distinct
//    from write buf. As overwrite at boundaries sits behind 2 barriers.
//  - ic boundaries now every 8 steps (16 total): stage_a (direct; T14 reg
//    variant spilled in round 2), lgkmcnt(0)+barrier, re-read af. Implicit
//    vmcnt(0) from x-load consumption accepted there.
//  - s_setprio(1) around the MFMA cluster; launch_bounds(256,4): 64 arch +
//    64 acc = 128 regs -> 4 blocks/CU with 37376 B LDS.
// ---------------------------------------------------------------------------
__global__ void __launch_bounds__(256, 4) conv_mfma_kernel(const float* __restrict__ xg,
                                                           const __bf16* __restrict__ wt,
                                                           float* __restrict__ out) {
  __shared__ __align__(16) __bf16 As[144 * 16];       // [143 rows][16 ch] 4608 B, swizzled
  __shared__ __align__(16) __bf16 Bs[4][128 * 32];    // ring-4 of [row o][32 e] 4x8192 B

  const int bx = blockIdx.x;
  const int nb = bx & 1;          // o-block 0..1
  const int mb = (bx >> 1) & 15;  // t-block 0..15
  const int b  = bx >> 5;         // batch   0..31

  const int tid  = threadIdx.x;
  const int w    = tid >> 6;
  const int lane = tid & 63;
  const int wm   = w >> 1, wn = w & 1;
  const int n16  = lane & 15, q = lane >> 4;

  const int t0 = mb * 128;
  const int o0 = nb * 128;

  const float* xbase = xg + (size_t)b * (S_ * CIN_);

  // B staging geometry (round-4 original, 2 gloads/wave, 16B/lane):
  const int br = w * 16 + (lane >> 2);
  const int bc = ((lane & 3) ^ ((lane >> 3) & 3)) * 8;  // T2 pre-swizzled source slot
  const int bswz = (n16 >> 1) & 3;                      // Bs read slot swizzle

  f32x4 acc[4][4];
  #pragma unroll
  for (int im_ = 0; im_ < 4; im_++)
    #pragma unroll
    for (int in_ = 0; in_ < 4; in_++)
      acc[im_][in_] = {0.f, 0.f, 0.f, 0.f};

  // ---- Stage A for ch-group g: rows 0..142 of x[t0+r][g*16..+16), bf16,
  // swizzled writes: byte ^= ((r>>3)&7)<<4 (slot-granular, 8B chunks safe).
  auto stage_a = [&](int g) {
    const int i0 = g * 16;
    #pragma unroll
    for (int p = 0; p < 3; p++) {
      int c = tid + p * 256;            // chunk = (row r = c>>2, 4 ch at (c&3)*4)
      if (c < 572) {                    // 143 rows * 4 chunks
        int r = c >> 2, sc = (c & 3) * 4;
        int rg = t0 + r; rg = (rg < S_) ? rg : (S_ - 1);
        float4 v = *(const float4*)(xbase + (size_t)rg * CIN_ + i0 + sc);
        bf16x4 o4; o4[0]=(__bf16)v.x; o4[1]=(__bf16)v.y; o4[2]=(__bf16)v.z; o4[3]=(__bf16)v.w;
        int byte = r * 32 + sc * 2;
        byte ^= ((r >> 3) & 7) << 4;    // == ((byte>>8)&7)<<4: involution
        *(bf16x4*)((char*)As + byte) = o4;
      }
    }
  };

  // ---- Stage B chunk for step jj into ring buffer buf (2 gloads/wave) ----
  auto stage_b = [&](int jj, int buf) {
    const __bf16* wcol = wt + (size_t)jj * 32 + bc;
    __bf16* dst = &Bs[0][0] + buf * (128 * 32) + (w * 16) * 32;
    #pragma unroll
    for (int p = 0; p < 2; p++) {
      int orow = o0 + p * 64 + br;
      gload_lds16(wcol + (size_t)orow * RTOT_, (void*)(dst + p * 64 * 32));
    }
  };

  // ---- Fragment reads (regs reused each iter; WAR vs MFMA orders them) ----
  bf16x8 af[4], bfrag[4];
  auto read_af = [&](int tp) {          // tp = tap-pair of target step
    #pragma unroll
    for (int jm = 0; jm < 4; jm++) {
      // A[m][e]: e = q*8+elem -> tap 2tp+(q>>1), ch (q&1)*8+elem
      int r = 2 * tp + wm * 64 + jm * 16 + n16 + (q >> 1);
      int byte = (r * 32 + (q & 1) * 16) ^ (((r >> 3) & 7) << 4);
      af[jm] = *(const bf16x8*)((const char*)As + byte);
    }
  };
  auto read_bf = [&](int buf) {
    const __bf16* bsr = &Bs[0][0] + buf * (128 * 32);
    #pragma unroll
    for (int jn = 0; jn < 4; jn++) {
      int row = wn * 64 + jn * 16 + n16;
      bfrag[jn] = *(const bf16x8*)(bsr + row * 32 + ((q ^ bswz) * 8));
    }
  };

  // ---- Prologue: A(g=0); B(0..2) staged; vmcnt(2) retires B(0),B(1) (B(2)
  // stays in flight); barrier publishes As + everyone's B(0),B(1); read(0).
  stage_a(0);
  stage_b(0, 0); stage_b(1, 1); stage_b(2, 2);
  asm volatile("s_waitcnt vmcnt(2) lgkmcnt(0)\n\ts_barrier" ::: "memory");
  read_af(0);
  read_bf(0);

  #pragma unroll 1
  for (int j = 0; j < 128; ++j) {
    if (j + 3 < 128) stage_b(j + 3, (j + 3) & 3);   // prefetch depth 3

    __builtin_amdgcn_s_setprio(1);
    #pragma unroll
    for (int jm = 0; jm < 4; jm++)
      #pragma unroll
      for (int jn = 0; jn < 4; jn++)
        acc[jm][jn] = __builtin_amdgcn_mfma_f32_16x16x32_bf16(af[jm], bfrag[jn], acc[jm][jn], 0, 0, 0);
    __builtin_amdgcn_s_setprio(0);

    if (j == 127) break;
    const bool bdry = ((j & 7) == 7);   // ic-group boundary (16 ch consumed)

    if (!bdry) read_af((j + 1) & 7);    // pre-barrier: As stable within group

    // Counted wait: retires B(j+2) (needed landed-everywhere before
    // barrier_j for iter j+1's pre-read); keeps B(j+3) in flight.
    if (j <= 124) asm volatile("s_waitcnt vmcnt(2)" ::: "memory");
    else          asm volatile("s_waitcnt vmcnt(0)" ::: "memory");
    read_bf((j + 1) & 3);               // pre-barrier: B(j+1) landed everywhere
                                        // (all waves retired it at end of j-1)
    asm volatile("s_barrier" ::: "memory");

    if (bdry) {
      // As overwrite: all As reads for this group completed pre-barrier_j.
      stage_a((j >> 3) + 1);
      asm volatile("s_waitcnt lgkmcnt(0)\n\ts_barrier" ::: "memory");
      read_af(0);                       // tp = (j+1)&7 = 0
    }
  }

  // ---- Epilogue: C/D layout col = lane&15, row = (lane>>4)*4 + reg ----
  float* obase = out + (size_t)b * TOUT_ * COUT_;
  #pragma unroll
  for (int jm = 0; jm < 4; jm++) {
    #pragma unroll
    for (int r = 0; r < 4; r++) {
      int t = t0 + wm * 64 + jm * 16 + q * 4 + r;
      if (t < TOUT_) {
        float* orow = obase + (size_t)t * COUT_ + o0 + wn * 64 + n16;
        #pragma unroll
        for (int jn = 0; jn < 4; jn++)
          orow[jn * 16] = acc[jm][jn][r];
      }
    }
  }
}

// ---------------------------------------------------------------------------
extern "C" void kernel_launch(void* const* d_in, const int* in_sizes, int n_in,
                              void* d_out, int out_size, void* d_ws, size_t ws_size,
                              hipStream_t stream) {
  const float* x  = (const float*)d_in[0];
  const float* wr = (const float*)d_in[1];
  const float* wi = (const float*)d_in[2];
  const float* ph = (const float*)d_in[3];
  float* out = (float*)d_out;

  __bf16* wt = (__bf16*)d_ws;  // 2 MB only

  build_wt_kernel<<<dim3((COUT_ * CIN_) / 256), dim3(256), 0, stream>>>(wr, wi, ph, wt);
  conv_mfma_kernel<<<dim3(B_ * 16 * 2), dim3(256), 0, stream>>>(x, wt, out);
}

// Round 7
// 225.853 us; speedup vs baseline: 1.1154x; 1.0339x over previous
//
#include <hip/hip_runtime.h>
#include <math.h>

// Problem constants
#define B_    32
#define S_    2048
#define CIN_  256
#define COUT_ 256
#define K_    16
#define TOUT_ 2033   // S - K + 1
#define RTOT_ 4096   // CIN * K reduction length

typedef __bf16 bf16x4 __attribute__((ext_vector_type(4)));
typedef __bf16 bf16x8 __attribute__((ext_vector_type(8)));
typedef float  f32x4  __attribute__((ext_vector_type(4)));

#define GLOBAL_AS __attribute__((address_space(1)))
#define LDS_AS    __attribute__((address_space(3)))

__device__ __forceinline__ void gload_lds16(const void* g, void* l) {
  // async global -> LDS: per-lane global gather, LDS dest = wave-uniform base + lane*16
  __builtin_amdgcn_global_load_lds((const GLOBAL_AS void*)g, (LDS_AS void*)l, 16, 0, 0);
}

// ---------------------------------------------------------------------------
// Build B^T in bf16:  wt[o][kk*256 + i] = cos(ph[kk])*w_real[o][i][kk]
//                                        - sin(ph[kk])*w_imag[o][i][kk]
// Row-major [COUT][RTOT] = 2 MB workspace (keep ws footprint tiny).
// (Round-6's (tap-pair,ch16) regroup reverted with the rest of round 6.)
// ---------------------------------------------------------------------------
__global__ void __launch_bounds__(256) build_wt_kernel(const float* __restrict__ wr,
                                                       const float* __restrict__ wi,
                                                       const float* __restrict__ ph,
                                                       __bf16* __restrict__ wt) {
  int t = blockIdx.x * 256 + threadIdx.x;   // 65536 threads: one per (o,i)
  int o = t >> 8, i = t & 255;
  const float4* wr4 = (const float4*)(wr + (size_t)(o * CIN_ + i) * K_);
  const float4* wi4 = (const float4*)(wi + (size_t)(o * CIN_ + i) * K_);
  float re[16], im[16];
  #pragma unroll
  for (int v = 0; v < 4; v++) {
    float4 a = wr4[v];
    re[4*v+0]=a.x; re[4*v+1]=a.y; re[4*v+2]=a.z; re[4*v+3]=a.w;
    float4 b = wi4[v];
    im[4*v+0]=b.x; im[4*v+1]=b.y; im[4*v+2]=b.z; im[4*v+3]=b.w;
  }
  #pragma unroll
  for (int kk = 0; kk < K_; kk++) {
    float p = ph[kk];
    wt[(size_t)o * RTOT_ + kk * CIN_ + i] = (__bf16)(cosf(p)*re[kk] - sinf(p)*im[kk]);
  }
}

// ---------------------------------------------------------------------------
// Main: implicit-GEMM conv = ROUND-4 VERIFIED BASE (128.8us, conflicts=0)
// with ONE surgical change: af(j+1) fragment reads moved PRE-barrier.
//
// Why (round-7): rounds 5/6 tested pre-barrier reads of BOTH operands and
// regressed for implementation reasons (self-staging duplication / As
// re-layout broke FETCH + swizzle). The A side alone needs NO new guarantee:
// As is stable within an ic, so read_af(j+1) before barrier_j is legal in
// round-4's exact structure. This moves 4 of the 8 post-barrier ds_reads
// into the barrier-convergence shadow (their lgkm waits complete during the
// barrier); after the barrier the MFMA cluster waits only on 4 bf reads.
// Zero extra registers (same af set; WAR vs MFMA(j) orders the reads),
// zero layout change, zero traffic change.
//   bf stays POST-barrier: with depth-2, other waves' B(j+1) loads are only
//   guaranteed retired at barrier_j (their vmcnt(2) precedes it) - the
//   exact hazard rounds 5/6 paid to work around. Not worth it.
//
// Pipeline (round 3/4):
//  - Bs 3-ring (3x8 KB), prefetch depth 2; LDS 33792 B -> 4 blocks/CU.
//  - One s_barrier/iter fused with counted s_waitcnt vmcnt(2); vmcnt(0)
//    only at the peeled final iter (j==126 stages nothing).
//  - Race ledger: stage writes buf (j+2)%3; bf reads buf j%3; af pre-reads
//    touch only As. As restage (bdry) is double-barrier fenced; the other
//    waves' last af reads completed before their MFMA(j), pre-barrier_j.
//  - A restage DIRECT at ic boundaries (T14 reg-prefetch spilled: round 2).
//  - T2 swizzle (round 4, conflicts -> 0): byte ^= ((row>>1)&3)<<4; As
//    swizzled on write+read; Bs pre-swizzled on the GLOBAL source
//    (slot = (lane&3)^((lane>>3)&3)), linear LDS dest (rule #21).
//  - s_setprio(1) around the 16-MFMA cluster; launch_bounds(256,4).
// ---------------------------------------------------------------------------
__global__ void __launch_bounds__(256, 4) conv_mfma_kernel(const float* __restrict__ xg,
                                                           const __bf16* __restrict__ wt,
                                                           float* __restrict__ out) {
  __shared__ __align__(16) __bf16 As[144 * 32];       // [row t-local][32 ch] 9216 B
  __shared__ __align__(16) __bf16 Bs[3][128 * 32];    // ring of [row o-local][32 k] 3x8192 B

  const int bx = blockIdx.x;
  const int nb = bx & 1;          // o-block 0..1
  const int mb = (bx >> 1) & 15;  // t-block 0..15
  const int b  = bx >> 5;         // batch   0..31

  const int tid  = threadIdx.x;
  const int w    = tid >> 6;
  const int lane = tid & 63;
  const int wm   = w >> 1, wn = w & 1;
  const int n16  = lane & 15, q = lane >> 4;

  const int t0 = mb * 128;
  const int o0 = nb * 128;

  const float* xbase = xg + (size_t)b * (S_ * CIN_);

  // A staging geometry (reg round-trip): thread -> (row sr, 4 fp32 at col sc)
  const int sr = tid >> 3;        // 0..31
  const int sc = (tid & 7) * 4;   // fp32/bf16 col offset (8B chunk; slot = sc>>3)
  // B staging geometry (global_load_lds, 16B/lane): wave w, issue p covers
  // rows p*64 + w*16 .. +16. Source slot carries the T2 pre-swizzle.
  const int br = w * 16 + (lane >> 2);
  const int bc = (((lane & 3) ^ ((lane >> 3) & 3))) * 8;   // T2 pre-swizzled source slot

  // T2 read-side slot swizzle for Bs (row bits [2:1] = n16 bits [2:1])
  const int bswz = (n16 >> 1) & 3;

  f32x4 acc[4][4];
  #pragma unroll
  for (int im_ = 0; im_ < 4; im_++)
    #pragma unroll
    for (int in_ = 0; in_ < 4; in_++)
      acc[im_][in_] = {0.f, 0.f, 0.f, 0.f};

  // ---- Stage A for channel group ic: rows 0..143 (x rows t0.., clamped) ----
  // T2: 8B chunk (orig col sc) lands at col sc ^ (((r>>1)&3)<<3).
  auto stage_a = [&](int ic) {
    const float* xcol = xbase + ic * 32 + sc;
    #pragma unroll
    for (int p = 0; p < 4; p++) {
      int r = p * 32 + sr;
      int rg = t0 + r; rg = (rg < S_) ? rg : (S_ - 1);
      float4 v = *(const float4*)(xcol + (size_t)rg * CIN_);
      bf16x4 o4; o4[0]=(__bf16)v.x; o4[1]=(__bf16)v.y; o4[2]=(__bf16)v.z; o4[3]=(__bf16)v.w;
      *(bf16x4*)(As + r * 32 + (sc ^ (((r >> 1) & 3) << 3))) = o4;
    }
    if (tid < 128) {  // tail rows 128..143
      int r = 128 + sr;
      int rg = t0 + r; rg = (rg < S_) ? rg : (S_ - 1);
      float4 v = *(const float4*)(xcol + (size_t)rg * CIN_);
      bf16x4 o4; o4[0]=(__bf16)v.x; o4[1]=(__bf16)v.y; o4[2]=(__bf16)v.z; o4[3]=(__bf16)v.w;
      *(bf16x4*)(As + r * 32 + (sc ^ (((r >> 1) & 3) << 3))) = o4;
    }
  };

  // ---- Stage B chunk for step j into ring buffer buf (2 gloads/wave) ----
  // T2: source column pre-swizzled via bc so the LINEAR LDS write yields the
  // swizzled tile (content at [row][slot] = orig slot ^ ((row>>1)&3)).
  auto stage_b = [&](int j, int buf) {
    const int kk = j & 15;
    const int i0 = (j >> 4) * 32;
    const __bf16* wcol = wt + (size_t)kk * CIN_ + i0 + bc;
    __bf16* dst = &Bs[0][0] + buf * (128 * 32) + (w * 16) * 32;
    #pragma unroll
    for (int p = 0; p < 2; p++) {
      int orow = o0 + p * 64 + br;
      gload_lds16(wcol + (size_t)orow * RTOT_, (void*)(dst + p * 64 * 32));
    }
  };

  // ---- Fragment reads (single af/bfrag sets, reused; WAR vs MFMA orders) --
  bf16x8 af[4], bfrag[4];
  auto read_af = [&](int kp) {      // kp = kk of the TARGET iteration
    const int aswz = ((kp + n16) >> 1) & 3;   // As row bits[2:1], uniform over jm
    #pragma unroll
    for (int jm = 0; jm < 4; jm++) {
      int row = kp + wm * 64 + jm * 16 + n16;    // A[m=lane&15][k=q*8+j]
      af[jm] = *(const bf16x8*)(As + row * 32 + ((q ^ aswz) * 8));
    }
  };
  auto read_bf = [&](int buf) {
    const __bf16* bsr = &Bs[0][0] + buf * (128 * 32);
    #pragma unroll
    for (int jn = 0; jn < 4; jn++) {
      int row = wn * 64 + jn * 16 + n16;         // B^T[n=lane&15][k=q*8+j]
      bfrag[jn] = *(const bf16x8*)(bsr + row * 32 + ((q ^ bswz) * 8));
    }
  };

  // ---- Prologue: A(ic=0) + B(0), B(1); wait B(0) landed, keep B(1) in
  // flight; barrier publishes As + everyone's B(0); pre-read af(0).
  stage_a(0);
  stage_b(0, 0);
  stage_b(1, 1);
  asm volatile("s_waitcnt vmcnt(2) lgkmcnt(0)\n\ts_barrier" ::: "memory");
  read_af(0);

  int jr = 0;   // read buffer  = j % 3
  int jw = 2;   // write buffer = (j+2) % 3
  #pragma unroll 1
  for (int j = 0; j < 128; ++j) {
    const int kk = j & 15;

    if (j + 2 < 128) stage_b(j + 2, jw);   // prefetch depth 2 (wave-uniform)

    read_bf(jr);                           // post-barrier: B(j) visible

    __builtin_amdgcn_s_setprio(1);
    #pragma unroll
    for (int jm = 0; jm < 4; jm++)
      #pragma unroll
      for (int jn = 0; jn < 4; jn++)
        acc[jm][jn] = __builtin_amdgcn_mfma_f32_16x16x32_bf16(af[jm], bfrag[jn], acc[jm][jn], 0, 0, 0);
    __builtin_amdgcn_s_setprio(0);

    if (j == 127) break;               // last step: no tail work

    const bool bdry = (kk == 15);
    if (!bdry) read_af(kk + 1);        // PRE-barrier: As stable within ic;
                                       // lgkm completes during barrier wait

    // Counted end-of-iter wait: B(j+1) complete (older), B(j+2) stays in
    // flight. j==126 issued nothing this iter -> must drain B(127) fully.
    if (j <= 125) asm volatile("s_waitcnt vmcnt(2)\n\ts_barrier" ::: "memory");
    else          asm volatile("s_waitcnt vmcnt(0)\n\ts_barrier" ::: "memory");

    if (bdry) {
      // ic boundary: all waves' af reads for this ic completed before their
      // MFMA(j), pre-barrier -> safe to overwrite. Direct restage, fence,
      // then pre-read the new ic's af(kk=0).
      stage_a((j + 1) >> 4);
      asm volatile("s_waitcnt lgkmcnt(0)\n\ts_barrier" ::: "memory");
      read_af(0);
    }

    jr = (jr == 2) ? 0 : jr + 1;
    jw = (jw == 2) ? 0 : jw + 1;
  }

  // ---- Epilogue: C/D layout col = lane&15, row = (lane>>4)*4 + reg ----
  float* obase = out + (size_t)b * TOUT_ * COUT_;
  #pragma unroll
  for (int jm = 0; jm < 4; jm++) {
    #pragma unroll
    for (int r = 0; r < 4; r++) {
      int t = t0 + wm * 64 + jm * 16 + q * 4 + r;
      if (t < TOUT_) {
        float* orow = obase + (size_t)t * COUT_ + o0 + wn * 64 + n16;
        #pragma unroll
        for (int jn = 0; jn < 4; jn++)
          orow[jn * 16] = acc[jm][jn][r];
      }
    }
  }
}

// ---------------------------------------------------------------------------
extern "C" void kernel_launch(void* const* d_in, const int* in_sizes, int n_in,
                              void* d_out, int out_size, void* d_ws, size_t ws_size,
                              hipStream_t stream) {
  const float* x  = (const float*)d_in[0];
  const float* wr = (const float*)d_in[1];
  const float* wi = (const float*)d_in[2];
  const float* ph = (const float*)d_in[3];
  float* out = (float*)d_out;

  __bf16* wt = (__bf16*)d_ws;  // 2 MB only

  build_wt_kernel<<<dim3((COUT_ * CIN_) / 256), dim3(256), 0, stream>>>(wr, wi, ph, wt);
  conv_mfma_kernel<<<dim3(B_ * 16 * 2), dim3(256), 0, stream>>>(x, wt, out);
}